// Round 1
// baseline (3037.760 us; speedup 1.0000x reference)
//
#include <hip/hip_runtime.h>
#include <hip/hip_bf16.h>
#include <float.h>

// Problem constants
constexpr int D_MODEL  = 1024;
constexpr int DICT     = 16384;
constexpr int TOPK     = 8;
constexpr int NTOK     = 4096;      // B*T = 2*2048
constexpr int CHUNK_T  = 1024;      // tokens per chunk (coeffs chunk = 67 MB, fits ws + LLC)
constexpr long long COEFF_COUNT = (long long)NTOK * DICT;  // 67108864

// GEMM tile config
constexpr int TM = 64;
constexpr int TN = 64;
constexpr int TKK = 32;

// ---------------------------------------------------------------------------
// Phase 1: coeffs[t][m] = sum_d x[t][d] * W_enc[m][d]   (fp32, NT gemm)
// Grid: (DICT/TN, CHUNK_T/TM), block 256 threads (16x16), 4x4 acc per thread.
// ---------------------------------------------------------------------------
__global__ __launch_bounds__(256) void ssod_gemm(const float* __restrict__ x,
                                                 const float* __restrict__ Wenc,
                                                 float* __restrict__ coeffs,
                                                 int tokBase) {
    __shared__ float As[TM][TKK + 1];
    __shared__ float Bs[TN][TKK + 1];

    const int tid = threadIdx.x;
    const int tx = tid & 15;        // n-direction
    const int ty = tid >> 4;        // m-direction
    const int bm = blockIdx.y;
    const int bn = blockIdx.x;

    const float* xrow = x + (size_t)(tokBase + bm * TM) * D_MODEL;
    const float* wrow = Wenc + (size_t)(bn * TN) * D_MODEL;

    float acc[4][4] = {};

    const int lr = tid >> 3;        // 0..31 row within half-tile
    const int lc = (tid & 7) * 4;   // 0,4,...,28 col

    for (int k0 = 0; k0 < D_MODEL; k0 += TKK) {
        // load 64x32 A-tile and B-tile; 2 passes of 32 rows, float4 per thread
        #pragma unroll
        for (int p = 0; p < 2; ++p) {
            const int r = p * 32 + lr;
            const float4 av = *(const float4*)(xrow + (size_t)r * D_MODEL + k0 + lc);
            As[r][lc + 0] = av.x; As[r][lc + 1] = av.y;
            As[r][lc + 2] = av.z; As[r][lc + 3] = av.w;
            const float4 bv = *(const float4*)(wrow + (size_t)r * D_MODEL + k0 + lc);
            Bs[r][lc + 0] = bv.x; Bs[r][lc + 1] = bv.y;
            Bs[r][lc + 2] = bv.z; Bs[r][lc + 3] = bv.w;
        }
        __syncthreads();

        #pragma unroll
        for (int kk = 0; kk < TKK; ++kk) {
            float a[4], b[4];
            #pragma unroll
            for (int i = 0; i < 4; ++i) a[i] = As[ty * 4 + i][kk];
            #pragma unroll
            for (int j = 0; j < 4; ++j) b[j] = Bs[tx * 4 + j][kk];
            #pragma unroll
            for (int i = 0; i < 4; ++i)
                #pragma unroll
                for (int j = 0; j < 4; ++j)
                    acc[i][j] += a[i] * b[j];
        }
        __syncthreads();
    }

    // store 4x4 block (coeffs indexed chunk-local)
    float* crow = coeffs + (size_t)(bm * TM + ty * 4) * DICT + bn * TN + tx * 4;
    #pragma unroll
    for (int i = 0; i < 4; ++i) {
        float4 v = make_float4(acc[i][0], acc[i][1], acc[i][2], acc[i][3]);
        *(float4*)(crow + (size_t)i * DICT) = v;
    }
}

// ---------------------------------------------------------------------------
// Phase 2: top-8 per token with lower-index tie-break (matches lax.top_k).
// One block (256 thr) per token; per-thread sorted-8 over 64 strided coeffs,
// then LDS tree merge.
// ---------------------------------------------------------------------------
__device__ __forceinline__ bool tk_better(float v1, int i1, float v2, int i2) {
    return (v1 > v2) || (v1 == v2 && i1 < i2);
}

__global__ __launch_bounds__(256) void ssod_topk(const float* __restrict__ coeffs,
                                                 float* __restrict__ tkv,
                                                 int* __restrict__ tki,
                                                 float* __restrict__ tsum,
                                                 int tokBase) {
    const int t = blockIdx.x;               // chunk-local token
    const int tid = threadIdx.x;
    const float* row = coeffs + (size_t)t * DICT;

    float v[TOPK];
    int   id[TOPK];
    #pragma unroll
    for (int j = 0; j < TOPK; ++j) { v[j] = -FLT_MAX; id[j] = 0x7fffffff; }

    for (int i = tid; i < DICT; i += 256) {
        const float val = row[i];
        if (tk_better(val, i, v[TOPK - 1], id[TOPK - 1])) {
            v[TOPK - 1] = val; id[TOPK - 1] = i;
            #pragma unroll
            for (int j = TOPK - 1; j > 0; --j) {
                if (tk_better(v[j], id[j], v[j - 1], id[j - 1])) {
                    float tv = v[j]; v[j] = v[j - 1]; v[j - 1] = tv;
                    int   ti = id[j]; id[j] = id[j - 1]; id[j - 1] = ti;
                } else break;
            }
        }
    }

    __shared__ float sv[256][TOPK];
    __shared__ int   si[256][TOPK];
    #pragma unroll
    for (int j = 0; j < TOPK; ++j) { sv[tid][j] = v[j]; si[tid][j] = id[j]; }
    __syncthreads();

    for (int s = 128; s >= 1; s >>= 1) {
        if (tid < s) {
            float av[TOPK], bv[TOPK], ov[TOPK];
            int   ai[TOPK], bi[TOPK], oi[TOPK];
            #pragma unroll
            for (int j = 0; j < TOPK; ++j) {
                av[j] = sv[tid][j];      ai[j] = si[tid][j];
                bv[j] = sv[tid + s][j];  bi[j] = si[tid + s][j];
            }
            int pa = 0, pb = 0;
            #pragma unroll
            for (int j = 0; j < TOPK; ++j) {
                const bool takeA = tk_better(av[pa], ai[pa], bv[pb], bi[pb]);
                if (takeA) { ov[j] = av[pa]; oi[j] = ai[pa]; ++pa; }
                else       { ov[j] = bv[pb]; oi[j] = bi[pb]; ++pb; }
            }
            #pragma unroll
            for (int j = 0; j < TOPK; ++j) { sv[tid][j] = ov[j]; si[tid][j] = oi[j]; }
        }
        __syncthreads();
    }

    const int gt = tokBase + t;
    if (tid < TOPK) {
        tkv[gt * TOPK + tid] = sv[0][tid];
        tki[gt * TOPK + tid] = si[0][tid];
    }
    if (tid == 0) {
        float s = 0.f;
        #pragma unroll
        for (int j = 0; j < TOPK; ++j) s += fabsf(sv[0][j]);
        tsum[gt] = s;
    }
}

// ---------------------------------------------------------------------------
// Phase 3: offset[t][d] = sum_k tkv[t][k] * W_dict[tki[t][k]][d]
// One block per token, 256 threads x float4 = 1024 dims.
// ---------------------------------------------------------------------------
__global__ __launch_bounds__(256) void ssod_offset(const float* __restrict__ tkv,
                                                   const int* __restrict__ tki,
                                                   const float* __restrict__ Wdict,
                                                   float* __restrict__ out) {
    const int t = blockIdx.x;
    const int tid = threadIdx.x;

    __shared__ float vals[TOPK];
    __shared__ int   idx[TOPK];
    if (tid < TOPK) {
        vals[tid] = tkv[t * TOPK + tid];
        idx[tid]  = tki[t * TOPK + tid];
    }
    __syncthreads();

    const int d = tid * 4;
    float4 acc = make_float4(0.f, 0.f, 0.f, 0.f);
    #pragma unroll
    for (int k = 0; k < TOPK; ++k) {
        const float4 r = *(const float4*)(Wdict + (size_t)idx[k] * D_MODEL + d);
        const float s = vals[k];
        acc.x += s * r.x; acc.y += s * r.y; acc.z += s * r.z; acc.w += s * r.w;
    }
    *(float4*)(out + (size_t)t * D_MODEL + d) = acc;
}

// ---------------------------------------------------------------------------
// Phase 4: sparsity_loss = sum(tsum) / (NTOK*DICT); single block.
// ---------------------------------------------------------------------------
__global__ __launch_bounds__(256) void ssod_loss(const float* __restrict__ tsum,
                                                 float* __restrict__ out) {
    float s = 0.f;
    for (int i = threadIdx.x; i < NTOK; i += 256) s += tsum[i];
    #pragma unroll
    for (int off = 32; off > 0; off >>= 1) s += __shfl_down(s, off, 64);
    __shared__ float wsum[4];
    if ((threadIdx.x & 63) == 0) wsum[threadIdx.x >> 6] = s;
    __syncthreads();
    if (threadIdx.x == 0) {
        const float tot = wsum[0] + wsum[1] + wsum[2] + wsum[3];
        out[(size_t)NTOK * D_MODEL] = tot / (float)COEFF_COUNT;
    }
}

// ---------------------------------------------------------------------------
extern "C" void kernel_launch(void* const* d_in, const int* in_sizes, int n_in,
                              void* d_out, int out_size, void* d_ws, size_t ws_size,
                              hipStream_t stream) {
    const float* x     = (const float*)d_in[0];   // [4096,1024]
    const float* Wenc  = (const float*)d_in[1];   // [16384,1024]
    const float* Wdict = (const float*)d_in[2];   // [16384,1024]
    float* out = (float*)d_out;                   // 4096*1024 offset + 1 loss

    // workspace layout
    char* ws = (char*)d_ws;
    float* coeffs = (float*)ws;                                    // CHUNK_T*DICT fp32 = 64 MB
    size_t off = (size_t)CHUNK_T * DICT * sizeof(float);
    float* tkv = (float*)(ws + off);   off += (size_t)NTOK * TOPK * sizeof(float);
    int*   tki = (int*)(ws + off);     off += (size_t)NTOK * TOPK * sizeof(int);
    float* tsum = (float*)(ws + off);

    for (int c = 0; c < NTOK / CHUNK_T; ++c) {
        const int tokBase = c * CHUNK_T;
        dim3 ggrid(DICT / TN, CHUNK_T / TM);
        ssod_gemm<<<ggrid, 256, 0, stream>>>(x, Wenc, coeffs, tokBase);
        ssod_topk<<<CHUNK_T, 256, 0, stream>>>(coeffs, tkv, tki, tsum, tokBase);
    }
    ssod_offset<<<NTOK, 256, 0, stream>>>(tkv, tki, Wdict, out);
    ssod_loss<<<1, 256, 0, stream>>>(tsum, out);
}

// Round 2
// 991.662 us; speedup vs baseline: 3.0633x; 3.0633x over previous
//
#include <hip/hip_runtime.h>
#include <float.h>
#include <stdint.h>

constexpr int D_MODEL = 1024;
constexpr int DICT    = 16384;
constexpr int TOPK    = 8;
constexpr int NCAND   = 16;
constexpr int NTOK    = 4096;      // B*T
constexpr long long COEFF_COUNT = (long long)NTOK * DICT;

typedef __attribute__((ext_vector_type(8))) __bf16 bf16x8;
typedef __attribute__((ext_vector_type(4))) float  floatx4;

__device__ __forceinline__ unsigned short f2bf(float f) {
    unsigned int u = __float_as_uint(f);
    u = u + 0x7fffu + ((u >> 16) & 1u);     // RNE
    return (unsigned short)(u >> 16);
}
__device__ __forceinline__ float bf2f(unsigned short h) {
    return __uint_as_float(((unsigned int)h) << 16);
}

__device__ __forceinline__ void async16(void* lds, const void* g) {
    __builtin_amdgcn_global_load_lds(
        (__attribute__((address_space(1))) void*)g,
        (__attribute__((address_space(3))) void*)lds, 16, 0, 0);
}

// ---------------------------------------------------------------------------
// fp32 -> bf16 bulk convert
// ---------------------------------------------------------------------------
__global__ __launch_bounds__(256) void ssod_cvt(const float4* __restrict__ src,
                                                ushort4* __restrict__ dst, int n4) {
    const int i = blockIdx.x * 256 + threadIdx.x;
    if (i < n4) {
        const float4 v = src[i];
        ushort4 o;
        o.x = f2bf(v.x); o.y = f2bf(v.y); o.z = f2bf(v.z); o.w = f2bf(v.w);
        dst[i] = o;
    }
}

// ---------------------------------------------------------------------------
// bf16 MFMA GEMM: C[m][n] = sum_k A[m][k]*B[n][k]  (both K-contiguous, BT form)
// 128x128 block tile, BK=32, 256 thr = 2x2 waves, wave = 64x64 (4x4 frags of
// 16x16x32). global_load_lds width 16 staging, unpadded LDS (m97 structure).
// A = x_bf16 chunk [chunkT][1024]; B = Wenc_bf16 [16384][1024];
// C = coeffs bf16 [chunkT][16384].
// ---------------------------------------------------------------------------
__global__ __launch_bounds__(256) void ssod_gemm_bf16(const unsigned short* __restrict__ A,
                                                      const unsigned short* __restrict__ B,
                                                      unsigned short* __restrict__ C) {
    __shared__ unsigned short As[128 * 32];
    __shared__ unsigned short Bs[128 * 32];

    const int tid  = threadIdx.x;
    const int wave = tid >> 6;
    const int lane = tid & 63;
    const int bn   = blockIdx.x;          // dict tile
    const int bm   = blockIdx.y;          // token tile
    const int wm   = wave >> 1;
    const int wn   = wave & 1;

    const unsigned short* Abase = A + (size_t)bm * 128 * D_MODEL;
    const unsigned short* Bbase = B + (size_t)bn * 128 * D_MODEL;

    floatx4 acc[4][4];
    #pragma unroll
    for (int i = 0; i < 4; ++i)
        #pragma unroll
        for (int j = 0; j < 4; ++j) acc[i][j] = floatx4{0.f, 0.f, 0.f, 0.f};

    // staging chunk ids: 16B chunk c covers row c>>2, kcols (c&3)*8..+7,
    // LDS elems c*8 (lane-contiguous per wave as global_load_lds requires)
    const int c0 = wave * 64 + lane;      // 0..255
    const int c1 = c0 + 256;              // 256..511

    const int fr = lane & 15;             // row within 16x16 frag
    const int kg = lane >> 4;             // k-group (8 elems each)

    for (int k0 = 0; k0 < D_MODEL; k0 += 32) {
        async16(&As[c0 * 8], Abase + (size_t)(c0 >> 2) * D_MODEL + k0 + (c0 & 3) * 8);
        async16(&As[c1 * 8], Abase + (size_t)(c1 >> 2) * D_MODEL + k0 + (c1 & 3) * 8);
        async16(&Bs[c0 * 8], Bbase + (size_t)(c0 >> 2) * D_MODEL + k0 + (c0 & 3) * 8);
        async16(&Bs[c1 * 8], Bbase + (size_t)(c1 >> 2) * D_MODEL + k0 + (c1 & 3) * 8);
        __syncthreads();   // drains vmcnt -> staging complete

        bf16x8 af[4], bfr[4];
        #pragma unroll
        for (int f = 0; f < 4; ++f) {
            af[f]  = *(const bf16x8*)&As[(wm * 64 + f * 16 + fr) * 32 + kg * 8];
            bfr[f] = *(const bf16x8*)&Bs[(wn * 64 + f * 16 + fr) * 32 + kg * 8];
        }
        #pragma unroll
        for (int i = 0; i < 4; ++i)
            #pragma unroll
            for (int j = 0; j < 4; ++j)
                acc[i][j] = __builtin_amdgcn_mfma_f32_16x16x32_bf16(af[i], bfr[j], acc[i][j], 0, 0, 0);
        __syncthreads();
    }

    // C/D layout: col = lane&15, row = (lane>>4)*4 + reg
    const int col = lane & 15;
    const int rq  = lane >> 4;
    #pragma unroll
    for (int i = 0; i < 4; ++i) {
        const int row = bm * 128 + wm * 64 + i * 16 + rq * 4;
        #pragma unroll
        for (int j = 0; j < 4; ++j) {
            const int ccol = bn * 128 + wn * 64 + j * 16 + col;
            unsigned short* cp = C + (size_t)row * DICT + ccol;
            #pragma unroll
            for (int r = 0; r < 4; ++r)
                cp[(size_t)r * DICT] = f2bf(acc[i][j][r]);
        }
    }
}

// ---------------------------------------------------------------------------
// top-16 candidates per token from bf16 coeffs (chunk-local).
// Per-thread sorted-16 over 64 elems (8x uint4 = 8 bf16 each), LDS tree merge.
// Ordering: (value desc, index asc) — deterministic superset of true top-8.
// ---------------------------------------------------------------------------
__device__ __forceinline__ bool tk_better(float v1, int i1, float v2, int i2) {
    return (v1 > v2) || (v1 == v2 && i1 < i2);
}

__global__ __launch_bounds__(256) void ssod_top16(const unsigned short* __restrict__ coeffs,
                                                  int* __restrict__ cand, int tokBase) {
    const int t   = blockIdx.x;
    const int tid = threadIdx.x;
    const unsigned short* row = coeffs + (size_t)t * DICT;

    float v[NCAND];
    int   id[NCAND];
    #pragma unroll
    for (int j = 0; j < NCAND; ++j) { v[j] = -FLT_MAX; id[j] = 0x7fffffff; }

    for (int it = 0; it < 8; ++it) {
        const int base = (it * 256 + tid) * 8;
        const uint4 pk = *(const uint4*)(row + base);
        const unsigned int w[4] = {pk.x, pk.y, pk.z, pk.w};
        #pragma unroll
        for (int j = 0; j < 8; ++j) {
            const float f  = bf2f((unsigned short)((w[j >> 1] >> ((j & 1) * 16)) & 0xffffu));
            const int   ix = base + j;
            if (tk_better(f, ix, v[NCAND - 1], id[NCAND - 1])) {
                v[NCAND - 1] = f; id[NCAND - 1] = ix;
                #pragma unroll
                for (int q = NCAND - 1; q > 0; --q) {
                    if (tk_better(v[q], id[q], v[q - 1], id[q - 1])) {
                        float tv = v[q]; v[q] = v[q - 1]; v[q - 1] = tv;
                        int   ti = id[q]; id[q] = id[q - 1]; id[q - 1] = ti;
                    } else break;
                }
            }
        }
    }

    __shared__ float sv[256][NCAND];
    __shared__ int   si[256][NCAND];
    #pragma unroll
    for (int j = 0; j < NCAND; ++j) { sv[tid][j] = v[j]; si[tid][j] = id[j]; }
    __syncthreads();

    for (int s = 128; s >= 1; s >>= 1) {
        if (tid < s) {
            float ov[NCAND]; int oi[NCAND];
            int pa = 0, pb = 0;
            #pragma unroll
            for (int j = 0; j < NCAND; ++j) {
                const float va = sv[tid][pa],     vb = sv[tid + s][pb];
                const int   ia = si[tid][pa],     ib = si[tid + s][pb];
                const bool takeA = tk_better(va, ia, vb, ib);
                ov[j] = takeA ? va : vb;
                oi[j] = takeA ? ia : ib;
                pa += takeA ? 1 : 0; pb += takeA ? 0 : 1;
            }
            #pragma unroll
            for (int j = 0; j < NCAND; ++j) { sv[tid][j] = ov[j]; si[tid][j] = oi[j]; }
        }
        __syncthreads();
    }

    if (tid < NCAND) cand[(size_t)(tokBase + t) * NCAND + tid] = si[0][tid];
}

// ---------------------------------------------------------------------------
// Refine: recompute candidate coeffs in fp32, pick exact top-8, fused offset.
// One block (4 waves) per token.
// ---------------------------------------------------------------------------
__global__ __launch_bounds__(256) void ssod_refine(const float* __restrict__ x,
                                                   const float* __restrict__ Wenc,
                                                   const float* __restrict__ Wdict,
                                                   const int* __restrict__ cand,
                                                   float* __restrict__ outp,
                                                   float* __restrict__ tsum) {
    const int t    = blockIdx.x;
    const int tid  = threadIdx.x;
    const int lane = tid & 63;
    const int wave = tid >> 6;

    __shared__ float xs[D_MODEL];
    __shared__ int   cidx[NCAND];
    __shared__ float cval[NCAND];
    __shared__ float sval[TOPK];
    __shared__ int   sidx[TOPK];

    ((float4*)xs)[tid] = ((const float4*)(x + (size_t)t * D_MODEL))[tid];
    if (tid < NCAND) cidx[tid] = cand[(size_t)t * NCAND + tid];
    __syncthreads();

    const float4* xs4 = (const float4*)xs;
    #pragma unroll
    for (int s = 0; s < 4; ++s) {
        const int c = s * 4 + wave;
        const float4* wr4 = (const float4*)(Wenc + (size_t)cidx[c] * D_MODEL);
        float sum = 0.f;
        #pragma unroll
        for (int m = 0; m < 4; ++m) {
            const float4 xv = xs4[m * 64 + lane];
            const float4 wv = wr4[m * 64 + lane];
            sum += xv.x * wv.x + xv.y * wv.y + xv.z * wv.z + xv.w * wv.w;
        }
        #pragma unroll
        for (int off = 32; off > 0; off >>= 1) sum += __shfl_down(sum, off, 64);
        if (lane == 0) cval[c] = sum;
    }
    __syncthreads();

    if (tid == 0) {
        bool used[NCAND] = {};
        float ssum = 0.f;
        for (int k = 0; k < TOPK; ++k) {
            int best = -1;
            for (int c = 0; c < NCAND; ++c) {
                if (used[c]) continue;
                if (best < 0 || tk_better(cval[c], cidx[c], cval[best], cidx[best])) best = c;
            }
            used[best] = true;
            sval[k] = cval[best]; sidx[k] = cidx[best];
            ssum += fabsf(cval[best]);
        }
        tsum[t] = ssum;
    }
    __syncthreads();

    const int d = tid * 4;
    float4 a = make_float4(0.f, 0.f, 0.f, 0.f);
    #pragma unroll
    for (int k = 0; k < TOPK; ++k) {
        const float4 r = *(const float4*)(Wdict + (size_t)sidx[k] * D_MODEL + d);
        const float s = sval[k];
        a.x += s * r.x; a.y += s * r.y; a.z += s * r.z; a.w += s * r.w;
    }
    *(float4*)(outp + (size_t)t * D_MODEL + d) = a;
}

// ---------------------------------------------------------------------------
// loss = sum(tsum) / (NTOK*DICT)
// ---------------------------------------------------------------------------
__global__ __launch_bounds__(256) void ssod_loss(const float* __restrict__ tsum,
                                                 float* __restrict__ out) {
    float s = 0.f;
    for (int i = threadIdx.x; i < NTOK; i += 256) s += tsum[i];
    #pragma unroll
    for (int off = 32; off > 0; off >>= 1) s += __shfl_down(s, off, 64);
    __shared__ float wsum[4];
    if ((threadIdx.x & 63) == 0) wsum[threadIdx.x >> 6] = s;
    __syncthreads();
    if (threadIdx.x == 0) {
        const float tot = wsum[0] + wsum[1] + wsum[2] + wsum[3];
        out[(size_t)NTOK * D_MODEL] = tot / (float)COEFF_COUNT;
    }
}

// ---------------------------------------------------------------------------
extern "C" void kernel_launch(void* const* d_in, const int* in_sizes, int n_in,
                              void* d_out, int out_size, void* d_ws, size_t ws_size,
                              hipStream_t stream) {
    const float* x     = (const float*)d_in[0];   // [4096,1024]
    const float* Wenc  = (const float*)d_in[1];   // [16384,1024]
    const float* Wdict = (const float*)d_in[2];   // [16384,1024]
    float* out = (float*)d_out;

    char* ws = (char*)d_ws;
    size_t off = 0;
    unsigned short* xbf  = (unsigned short*)(ws + off); off += (size_t)NTOK * D_MODEL * 2;  // 8 MB
    unsigned short* wbf  = (unsigned short*)(ws + off); off += (size_t)DICT * D_MODEL * 2;  // 33.6 MB
    int*   cand = (int*)(ws + off);                     off += (size_t)NTOK * NCAND * 4;    // 256 KB
    float* tsum = (float*)(ws + off);                   off += (size_t)NTOK * 4;            // 16 KB
    unsigned short* coeffs = (unsigned short*)(ws + off);

    // pick largest token chunk whose bf16 coeff buffer fits remaining ws
    const size_t remain = (ws_size > off) ? (ws_size - off) : 0;
    int chunk = 512;                                   // 16.8 MB — fits round-1-proven floor
    if (remain >= (size_t)2048 * DICT * 2) chunk = 2048;
    else if (remain >= (size_t)1024 * DICT * 2) chunk = 1024;

    ssod_cvt<<<(NTOK * D_MODEL / 4) / 256, 256, 0, stream>>>((const float4*)x, (ushort4*)xbf, NTOK * D_MODEL / 4);
    ssod_cvt<<<(DICT * D_MODEL / 4) / 256, 256, 0, stream>>>((const float4*)Wenc, (ushort4*)wbf, DICT * D_MODEL / 4);

    for (int tokBase = 0; tokBase < NTOK; tokBase += chunk) {
        dim3 g(DICT / 128, chunk / 128);
        ssod_gemm_bf16<<<g, 256, 0, stream>>>(xbf + (size_t)tokBase * D_MODEL, wbf, coeffs);
        ssod_top16<<<chunk, 256, 0, stream>>>(coeffs, cand, tokBase);
    }

    ssod_refine<<<NTOK, 256, 0, stream>>>(x, Wenc, Wdict, cand, out, tsum);
    ssod_loss<<<1, 256, 0, stream>>>(tsum, out);
}

// Round 3
// 413.153 us; speedup vs baseline: 7.3526x; 2.4002x over previous
//
#include <hip/hip_runtime.h>
#include <float.h>
#include <stdint.h>

constexpr int D_MODEL = 1024;
constexpr int DICT    = 16384;
constexpr int TOPK    = 8;
constexpr int NCAND   = 16;
constexpr int NTOK    = 4096;      // B*T
constexpr long long COEFF_COUNT = (long long)NTOK * DICT;

typedef __attribute__((ext_vector_type(8))) __bf16 bf16x8;
typedef __attribute__((ext_vector_type(4))) float  floatx4;

__device__ __forceinline__ unsigned short f2bf(float f) {
    unsigned int u = __float_as_uint(f);
    u = u + 0x7fffu + ((u >> 16) & 1u);     // RNE
    return (unsigned short)(u >> 16);
}

__device__ __forceinline__ void async16(void* lds, const void* g) {
    __builtin_amdgcn_global_load_lds(
        (__attribute__((address_space(1))) void*)g,
        (__attribute__((address_space(3))) void*)lds, 16, 0, 0);
}

// ---------------------------------------------------------------------------
// fp32 -> bf16 bulk convert
// ---------------------------------------------------------------------------
__global__ __launch_bounds__(256) void ssod_cvt(const float4* __restrict__ src,
                                                ushort4* __restrict__ dst, int n4) {
    const int i = blockIdx.x * 256 + threadIdx.x;
    if (i < n4) {
        const float4 v = src[i];
        ushort4 o;
        o.x = f2bf(v.x); o.y = f2bf(v.y); o.z = f2bf(v.z); o.w = f2bf(v.w);
        dst[i] = o;
    }
}

// ---------------------------------------------------------------------------
// bf16 MFMA GEMM (m97 structure): 128x128 tile, BK=32, 2x2 waves, 4x4 frags.
// ---------------------------------------------------------------------------
__global__ __launch_bounds__(256) void ssod_gemm_bf16(const unsigned short* __restrict__ A,
                                                      const unsigned short* __restrict__ B,
                                                      unsigned short* __restrict__ C) {
    __shared__ unsigned short As[128 * 32];
    __shared__ unsigned short Bs[128 * 32];

    const int tid  = threadIdx.x;
    const int wave = tid >> 6;
    const int lane = tid & 63;
    const int bn   = blockIdx.x;          // dict tile
    const int bm   = blockIdx.y;          // token tile
    const int wm   = wave >> 1;
    const int wn   = wave & 1;

    const unsigned short* Abase = A + (size_t)bm * 128 * D_MODEL;
    const unsigned short* Bbase = B + (size_t)bn * 128 * D_MODEL;

    floatx4 acc[4][4];
    #pragma unroll
    for (int i = 0; i < 4; ++i)
        #pragma unroll
        for (int j = 0; j < 4; ++j) acc[i][j] = floatx4{0.f, 0.f, 0.f, 0.f};

    const int c0 = wave * 64 + lane;      // 0..255
    const int c1 = c0 + 256;              // 256..511

    const int fr = lane & 15;             // row within 16x16 frag
    const int kg = lane >> 4;             // k-group (8 elems each)

    for (int k0 = 0; k0 < D_MODEL; k0 += 32) {
        async16(&As[c0 * 8], Abase + (size_t)(c0 >> 2) * D_MODEL + k0 + (c0 & 3) * 8);
        async16(&As[c1 * 8], Abase + (size_t)(c1 >> 2) * D_MODEL + k0 + (c1 & 3) * 8);
        async16(&Bs[c0 * 8], Bbase + (size_t)(c0 >> 2) * D_MODEL + k0 + (c0 & 3) * 8);
        async16(&Bs[c1 * 8], Bbase + (size_t)(c1 >> 2) * D_MODEL + k0 + (c1 & 3) * 8);
        __syncthreads();

        bf16x8 af[4], bfr[4];
        #pragma unroll
        for (int f = 0; f < 4; ++f) {
            af[f]  = *(const bf16x8*)&As[(wm * 64 + f * 16 + fr) * 32 + kg * 8];
            bfr[f] = *(const bf16x8*)&Bs[(wn * 64 + f * 16 + fr) * 32 + kg * 8];
        }
        #pragma unroll
        for (int i = 0; i < 4; ++i)
            #pragma unroll
            for (int j = 0; j < 4; ++j)
                acc[i][j] = __builtin_amdgcn_mfma_f32_16x16x32_bf16(af[i], bfr[j], acc[i][j], 0, 0, 0);
        __syncthreads();
    }

    const int col = lane & 15;
    const int rq  = lane >> 4;
    #pragma unroll
    for (int i = 0; i < 4; ++i) {
        const int row = bm * 128 + wm * 64 + i * 16 + rq * 4;
        #pragma unroll
        for (int j = 0; j < 4; ++j) {
            const int ccol = bn * 128 + wn * 64 + j * 16 + col;
            unsigned short* cp = C + (size_t)row * DICT + ccol;
            #pragma unroll
            for (int r = 0; r < 4; ++r)
                cp[(size_t)r * DICT] = f2bf(acc[i][j][r]);
        }
    }
}

// ---------------------------------------------------------------------------
// Fast exact top-16 per token: threshold filter + collect + small sort.
// Keys: mono16 = bf16bits ^ 0x8000 (exact order among positives; top-16
// region is always strongly positive). Full key = (mono<<16)|(16383-idx)
// so uint-desc == (value desc, index asc).
// ---------------------------------------------------------------------------
__global__ __launch_bounds__(256) void ssod_top16(const unsigned short* __restrict__ coeffs,
                                                  int* __restrict__ cand, int tokBase) {
    const int t    = blockIdx.x;
    const int tid  = threadIdx.x;
    const int lane = tid & 63;
    const int wave = tid >> 6;
    const uint4* row4 = (const uint4*)(coeffs + (size_t)t * DICT);

    // load entire row slice into registers (coalesced 16B/lane), xor to mono
    unsigned int d[32];
    #pragma unroll
    for (int i = 0; i < 8; ++i) {
        const uint4 p = row4[i * 256 + tid];
        d[i * 4 + 0] = p.x ^ 0x80008000u;
        d[i * 4 + 1] = p.y ^ 0x80008000u;
        d[i * 4 + 2] = p.z ^ 0x80008000u;
        d[i * 4 + 3] = p.w ^ 0x80008000u;
    }

    // per-thread max of 64 mono keys
    unsigned int mx = 0;
    #pragma unroll
    for (int r = 0; r < 32; ++r) {
        const unsigned int hi = d[r] >> 16, lo = d[r] & 0xFFFFu;
        mx = max(mx, max(hi, lo));
    }

    __shared__ unsigned int smax[256];
    __shared__ unsigned int keys[128];
    __shared__ int cnt;
    __shared__ unsigned int sTau;
    smax[tid] = mx;
    if (tid == 0) cnt = 0;
    __syncthreads();

    // wave 0: tau = 16th-largest of 64 group-of-4 maxes (>=16 elems >= tau)
    if (wave == 0) {
        unsigned int g = max(max(smax[4 * lane + 0], smax[4 * lane + 1]),
                             max(smax[4 * lane + 2], smax[4 * lane + 3]));
        for (int k = 2; k <= 64; k <<= 1) {
            for (int j = k >> 1; j >= 1; j >>= 1) {
                const unsigned int p = __shfl_xor(g, j, 64);
                const bool tm = ((lane & j) == 0) ^ ((lane & k) != 0);
                g = tm ? max(g, p) : min(g, p);
            }
        }
        if (lane == 15) sTau = g;    // descending sort: lane 15 = 16th largest
    }
    __syncthreads();
    const unsigned int tau = sTau;

    // collect all elems with mono >= tau (expected ~18, cap 128, min 16)
    #pragma unroll
    for (int r = 0; r < 32; ++r) {
        const unsigned int hi = d[r] >> 16, lo = d[r] & 0xFFFFu;
        const int idx = 8 * ((r >> 2) * 256 + tid) + 2 * (r & 3);
        if (lo >= tau) {
            const int p = atomicAdd(&cnt, 1);
            if (p < 128) keys[p] = (lo << 16) | (unsigned)(16383 - idx);
        }
        if (hi >= tau) {
            const int p = atomicAdd(&cnt, 1);
            if (p < 128) keys[p] = (hi << 16) | (unsigned)(16383 - (idx + 1));
        }
    }
    __syncthreads();
    const int m = min(cnt, 128);
    for (int i = m + tid; i < 128; i += 256) keys[i] = 0;   // pad sorts last
    __syncthreads();

    // wave 0: bitonic sort 128 keys descending (2 regs/lane), emit top-16
    if (wave == 0) {
        unsigned int v0 = keys[lane], v1 = keys[lane + 64];
        for (int k = 2; k <= 128; k <<= 1) {
            for (int j = k >> 1; j >= 1; j >>= 1) {
                if (j == 64) {                      // only at k=128: cross-reg CE
                    const unsigned int a = max(v0, v1), b = min(v0, v1);
                    v0 = a; v1 = b;
                } else {
                    const unsigned int p0 = __shfl_xor(v0, j, 64);
                    const unsigned int p1 = __shfl_xor(v1, j, 64);
                    const bool tm0 = ((lane & j) == 0) ^ ((( lane       ) & k) != 0);
                    const bool tm1 = ((lane & j) == 0) ^ (((lane + 64) & k) != 0);
                    v0 = tm0 ? max(v0, p0) : min(v0, p0);
                    v1 = tm1 ? max(v1, p1) : min(v1, p1);
                }
            }
        }
        if (lane < NCAND)
            cand[(size_t)(tokBase + t) * NCAND + lane] = 16383 - (int)(v0 & 0xFFFFu);
    }
}

// ---------------------------------------------------------------------------
// Refine: recompute candidate coeffs in fp32, pick exact top-8, fused offset.
// ---------------------------------------------------------------------------
__device__ __forceinline__ bool tk_better(float v1, int i1, float v2, int i2) {
    return (v1 > v2) || (v1 == v2 && i1 < i2);
}

__global__ __launch_bounds__(256) void ssod_refine(const float* __restrict__ x,
                                                   const float* __restrict__ Wenc,
                                                   const float* __restrict__ Wdict,
                                                   const int* __restrict__ cand,
                                                   float* __restrict__ outp,
                                                   float* __restrict__ tsum) {
    const int t    = blockIdx.x;
    const int tid  = threadIdx.x;
    const int lane = tid & 63;
    const int wave = tid >> 6;

    __shared__ float xs[D_MODEL];
    __shared__ int   cidx[NCAND];
    __shared__ float cval[NCAND];
    __shared__ float sval[TOPK];
    __shared__ int   sidx[TOPK];

    ((float4*)xs)[tid] = ((const float4*)(x + (size_t)t * D_MODEL))[tid];
    if (tid < NCAND) cidx[tid] = cand[(size_t)t * NCAND + tid];
    __syncthreads();

    const float4* xs4 = (const float4*)xs;
    #pragma unroll
    for (int s = 0; s < 4; ++s) {
        const int c = s * 4 + wave;
        const float4* wr4 = (const float4*)(Wenc + (size_t)cidx[c] * D_MODEL);
        float sum = 0.f;
        #pragma unroll
        for (int m = 0; m < 4; ++m) {
            const float4 xv = xs4[m * 64 + lane];
            const float4 wv = wr4[m * 64 + lane];
            sum += xv.x * wv.x + xv.y * wv.y + xv.z * wv.z + xv.w * wv.w;
        }
        #pragma unroll
        for (int off = 32; off > 0; off >>= 1) sum += __shfl_down(sum, off, 64);
        if (lane == 0) cval[c] = sum;
    }
    __syncthreads();

    if (tid == 0) {
        bool used[NCAND] = {};
        float ssum = 0.f;
        for (int k = 0; k < TOPK; ++k) {
            int best = -1;
            for (int c = 0; c < NCAND; ++c) {
                if (used[c]) continue;
                if (best < 0 || tk_better(cval[c], cidx[c], cval[best], cidx[best])) best = c;
            }
            used[best] = true;
            sval[k] = cval[best]; sidx[k] = cidx[best];
            ssum += fabsf(cval[best]);
        }
        tsum[t] = ssum;
    }
    __syncthreads();

    const int d = tid * 4;
    float4 a = make_float4(0.f, 0.f, 0.f, 0.f);
    #pragma unroll
    for (int k = 0; k < TOPK; ++k) {
        const float4 r = *(const float4*)(Wdict + (size_t)sidx[k] * D_MODEL + d);
        const float s = sval[k];
        a.x += s * r.x; a.y += s * r.y; a.z += s * r.z; a.w += s * r.w;
    }
    *(float4*)(outp + (size_t)t * D_MODEL + d) = a;
}

// ---------------------------------------------------------------------------
// loss = sum(tsum) / (NTOK*DICT)
// ---------------------------------------------------------------------------
__global__ __launch_bounds__(256) void ssod_loss(const float* __restrict__ tsum,
                                                 float* __restrict__ out) {
    float s = 0.f;
    for (int i = threadIdx.x; i < NTOK; i += 256) s += tsum[i];
    #pragma unroll
    for (int off = 32; off > 0; off >>= 1) s += __shfl_down(s, off, 64);
    __shared__ float wsum[4];
    if ((threadIdx.x & 63) == 0) wsum[threadIdx.x >> 6] = s;
    __syncthreads();
    if (threadIdx.x == 0) {
        const float tot = wsum[0] + wsum[1] + wsum[2] + wsum[3];
        out[(size_t)NTOK * D_MODEL] = tot / (float)COEFF_COUNT;
    }
}

// ---------------------------------------------------------------------------
extern "C" void kernel_launch(void* const* d_in, const int* in_sizes, int n_in,
                              void* d_out, int out_size, void* d_ws, size_t ws_size,
                              hipStream_t stream) {
    const float* x     = (const float*)d_in[0];   // [4096,1024]
    const float* Wenc  = (const float*)d_in[1];   // [16384,1024]
    const float* Wdict = (const float*)d_in[2];   // [16384,1024]
    float* out = (float*)d_out;

    char* ws = (char*)d_ws;
    size_t off = 0;
    unsigned short* xbf  = (unsigned short*)(ws + off); off += (size_t)NTOK * D_MODEL * 2;  // 8 MB
    unsigned short* wbf  = (unsigned short*)(ws + off); off += (size_t)DICT * D_MODEL * 2;  // 33.6 MB
    int*   cand = (int*)(ws + off);                     off += (size_t)NTOK * NCAND * 4;    // 256 KB
    float* tsum = (float*)(ws + off);                   off += (size_t)NTOK * 4;            // 16 KB
    unsigned short* coeffs = (unsigned short*)(ws + off);

    const size_t remain = (ws_size > off) ? (ws_size - off) : 0;
    int chunk = 512;
    if (remain >= (size_t)2048 * DICT * 2) chunk = 2048;
    else if (remain >= (size_t)1024 * DICT * 2) chunk = 1024;

    ssod_cvt<<<(NTOK * D_MODEL / 4) / 256, 256, 0, stream>>>((const float4*)x, (ushort4*)xbf, NTOK * D_MODEL / 4);
    ssod_cvt<<<(DICT * D_MODEL / 4) / 256, 256, 0, stream>>>((const float4*)Wenc, (ushort4*)wbf, DICT * D_MODEL / 4);

    for (int tokBase = 0; tokBase < NTOK; tokBase += chunk) {
        dim3 g(DICT / 128, chunk / 128);
        ssod_gemm_bf16<<<g, 256, 0, stream>>>(xbf + (size_t)tokBase * D_MODEL, wbf, coeffs);
        ssod_top16<<<chunk, 256, 0, stream>>>(coeffs, cand, tokBase);
    }

    ssod_refine<<<NTOK, 256, 0, stream>>>(x, Wenc, Wdict, cand, out, tsum);
    ssod_loss<<<1, 256, 0, stream>>>(tsum, out);
}